// Round 1
// baseline (92.704 us; speedup 1.0000x reference)
//
#include <hip/hip_runtime.h>

// 8-qubit statevector sim. 4 samples per wave64: 16 lanes/sample, 16 amps/lane.
// Amp index i (8 bits): qubit q<=3 -> lane bit (3-q); qubit q>=4 -> reg bit (7-q).
// CNOT chains deferred into gate conjugation masks (validated in R1):
//   layer-l gate on qubit q pairs i with i^m, m = L^{-l} e_q  (components d, (l&d)==d)
//   row selector s = parity(i & row_q(L^l))                    (offsets d, selon(l,d))
// Fused U = RZ*RY*RX has u11 = conj(u00), u10 = -conj(u01)  =>  row selection is
// just sign flips on Im(u00) and Re(u01), applied via xor 0x80000000.
//
// R2: cross-lane xor exchanges moved from ds_swizzle (shared per-CU DS pipe,
// ~512 DS ops/wave = ~20us of serialized DS time across 16 waves/CU, plus
// lgkmcnt stalls) to DPP row ops on the VALU pipe (2 cyc, per-SIMD, no waits).
// xor masks within a 16-lane row:
//   1/2/3 -> quad_perm, 7 -> row_half_mirror, 8 -> row_ror:8, 15 -> row_mirror
//   composite (4,5,6,10,12,...) -> two chained DPP movs (xor masks compose).
// Permutation is identical to the swizzle version => bit-exact results.

#define NGATES 32

constexpr bool selon(int l, int d) {
    return (l == 0) ? (d == 0) : (((d + l - 1) & (l - 1)) == (l - 1));
}
// pair mask, lane part (qubits 0..3 -> lane bit 3-q)
constexpr int lm_of(int l, int q) {
    int m = 0;
    for (int d = 0; q + d <= 7; ++d)
        if ((l & d) == d) { int qq = q + d; if (qq <= 3) m |= 1 << (3 - qq); }
    return m;
}
// pair mask, register part (qubits 4..7 -> reg bit 7-q)
constexpr int rm_of(int l, int q) {
    int m = 0;
    for (int d = 0; q + d <= 7; ++d)
        if ((l & d) == d) { int qq = q + d; if (qq >= 4) m |= 1 << (7 - qq); }
    return m;
}
// selector mask, lane part
constexpr int slm_of(int l, int q) {
    int m = 0;
    for (int d = 0; d <= q; ++d)
        if (selon(l, d)) { int k = q - d; if (k <= 3) m |= 1 << (3 - k); }
    return m;
}
// selector mask, register part
constexpr int srm_of(int l, int q) {
    int m = 0;
    for (int d = 0; d <= q; ++d)
        if (selon(l, d)) { int k = q - d; if (k >= 4) m |= 1 << (7 - k); }
    return m;
}

__device__ __forceinline__ float xsgn(float f, unsigned m) {
    return __int_as_float(__float_as_int(f) ^ (int)m);
}

// single DPP mov, compile-time ctrl; full row/bank masks, all lanes valid
template<int C>
__device__ __forceinline__ int dppmov(int x) {
    return __builtin_amdgcn_update_dpp(x, x, C, 0xF, 0xF, false);
}

// DPP ctrl encodings (gfx9/CDNA):
//   quad_perm[p0,p1,p2,p3] = p0|p1<<2|p2<<4|p3<<6
//   xor1 = [1,0,3,2] = 0xB1 ; xor2 = [2,3,0,1] = 0x4E ; xor3 = [3,2,1,0] = 0x1B
//   row_half_mirror (xor7) = 0x141 ; row_mirror (xor15) = 0x140
//   row_ror:8 (xor8 in a 16-row) = 0x128
template<int M>
__device__ __forceinline__ float shx(float v) {
    static_assert(M >= 1 && M <= 15, "xor mask out of range");
    int x = __float_as_int(v);
    if constexpr (M == 1)       { x = dppmov<0xB1>(x); }
    else if constexpr (M == 2)  { x = dppmov<0x4E>(x); }
    else if constexpr (M == 3)  { x = dppmov<0x1B>(x); }
    else if constexpr (M == 4)  { x = dppmov<0x1B>(x);  x = dppmov<0x141>(x); } // 3^7
    else if constexpr (M == 5)  { x = dppmov<0x4E>(x);  x = dppmov<0x141>(x); } // 2^7
    else if constexpr (M == 6)  { x = dppmov<0xB1>(x);  x = dppmov<0x141>(x); } // 1^7
    else if constexpr (M == 7)  { x = dppmov<0x141>(x); }
    else if constexpr (M == 8)  { x = dppmov<0x128>(x); }
    else if constexpr (M == 9)  { x = dppmov<0xB1>(x);  x = dppmov<0x128>(x); } // 1^8
    else if constexpr (M == 10) { x = dppmov<0x4E>(x);  x = dppmov<0x128>(x); } // 2^8
    else if constexpr (M == 11) { x = dppmov<0x1B>(x);  x = dppmov<0x128>(x); } // 3^8
    else if constexpr (M == 12) { x = dppmov<0x140>(x); x = dppmov<0x1B>(x);  } // 15^3
    else if constexpr (M == 13) { x = dppmov<0x140>(x); x = dppmov<0x4E>(x);  } // 15^2
    else if constexpr (M == 14) { x = dppmov<0x140>(x); x = dppmov<0xB1>(x);  } // 15^1
    else                        { x = dppmov<0x140>(x); }                        // 15
    return __int_as_float(x);
}

template<int LM, int RM, int SLM, int SRM>
__device__ __forceinline__ void apply_gate(float ar[16], float ai[16], int lane,
                                           const float4 g)  // u00r,u00i,u01r,u01i
{
    unsigned sm = 0;
    if constexpr (SLM != 0)
        sm = (unsigned)((__builtin_popcount(lane & SLM) & 1) << 31);
    const float c0r = g.x, c1i = g.w;
    const float c0i0 = xsgn(g.y, sm);
    const float c1r0 = xsgn(g.z, sm);
    const float c0i1 = xsgn(g.y, sm ^ 0x80000000u);
    const float c1r1 = xsgn(g.z, sm ^ 0x80000000u);

    if constexpr (RM == 0) {
        // pure cross-lane: each r independent, partner = DPP-permuted self-register
        #pragma unroll
        for (int r = 0; r < 16; ++r) {
            const bool c1 = (__builtin_popcount(r & SRM) & 1) != 0;
            const float c0i = c1 ? c0i1 : c0i0;
            const float c1r = c1 ? c1r1 : c1r0;
            const float br = shx<LM>(ar[r]);
            const float bi = shx<LM>(ai[r]);
            const float nr = c0r*ar[r] - c0i*ai[r] + c1r*br - c1i*bi;
            const float ni = c0r*ai[r] + c0i*ar[r] + c1r*bi + c1i*br;
            ar[r] = nr; ai[r] = ni;
        }
    } else {
        // register pairs {r, r^RM}; fetch olds (DPP-permuted if LM!=0), update both
        #pragma unroll
        for (int r = 0; r < 16; ++r) {
            const int p = r ^ RM;
            if (p < r) continue;
            float br_r, bi_r, br_p, bi_p;
            if constexpr (LM != 0) {
                br_r = shx<LM>(ar[p]); bi_r = shx<LM>(ai[p]);
                br_p = shx<LM>(ar[r]); bi_p = shx<LM>(ai[r]);
            } else {
                br_r = ar[p]; bi_r = ai[p];
                br_p = ar[r]; bi_p = ai[r];
            }
            const bool cr = (__builtin_popcount(r & SRM) & 1) != 0;
            const bool cp = (__builtin_popcount(p & SRM) & 1) != 0;
            const float c0i_r = cr ? c0i1 : c0i0, c1r_r = cr ? c1r1 : c1r0;
            const float c0i_p = cp ? c0i1 : c0i0, c1r_p = cp ? c1r1 : c1r0;
            const float nr_r = c0r*ar[r] - c0i_r*ai[r] + c1r_r*br_r - c1i*bi_r;
            const float ni_r = c0r*ai[r] + c0i_r*ar[r] + c1r_r*bi_r + c1i*br_r;
            const float nr_p = c0r*ar[p] - c0i_p*ai[p] + c1r_p*br_p - c1i*bi_p;
            const float ni_p = c0r*ai[p] + c0i_p*ar[p] + c1r_p*bi_p + c1i*br_p;
            ar[r] = nr_r; ai[r] = ni_r;
            ar[p] = nr_p; ai[p] = ni_p;
        }
    }
}

#define GATE(L, Q) apply_gate<lm_of(L,Q), rm_of(L,Q), slm_of(L,Q), srm_of(L,Q)>( \
                       ar, ai, lane, gsh4[(L)*8+(Q)])
#define LAYER(L) GATE(L,0); GATE(L,1); GATE(L,2); GATE(L,3); \
                 GATE(L,4); GATE(L,5); GATE(L,6); GATE(L,7);

__global__ __launch_bounds__(256, 4) void qsim(const float* __restrict__ x,
                                               const float* __restrict__ w,
                                               float* __restrict__ out, int B)
{
    __shared__ float4 gsh4[NGATES];  // u00r,u00i,u01r,u01i (row1 = conj structure)

    const int tid = threadIdx.x;
    if (tid < NGATES) {
        float hx = 0.5f * w[tid*3+0];
        float hy = 0.5f * w[tid*3+1];
        float hz = 0.5f * w[tid*3+2];
        float cx = cosf(hx), sx = sinf(hx);
        float cy = cosf(hy), sy = sinf(hy);
        float cz = cosf(hz), sz = sinf(hz);
        // M = RY*RX ; U = RZ*M (row0 only; u11=conj(u00), u10=-conj(u01))
        float m00r = cy*cx,  m00i =  sy*sx;
        float m01r = -sy*cx, m01i = -cy*sx;
        gsh4[tid] = make_float4(cz*m00r + sz*m00i,
                                cz*m00i - sz*m00r,
                                cz*m01r + sz*m01i,
                                cz*m01i - sz*m01r);
    }
    __syncthreads();

    const int lane = tid & 63;
    const int il   = lane & 15;                 // in-sample lane index (amp bits 7:4)
    const int sample = blockIdx.x * 16 + (tid >> 4);
    if (sample >= B) return;

    // ---- encoding: product state ----
    const float4* xp = (const float4*)(x + sample * 8);
    float4 xa = xp[0], xb = xp[1];
    float xs[8] = {xa.x, xa.y, xa.z, xa.w, xb.x, xb.y, xb.z, xb.w};
    float cq[8], sq[8];
    #pragma unroll
    for (int q = 0; q < 8; ++q) {
        float h = 0.5f * xs[q];
        __sincosf(h, &sq[q], &cq[q]);
    }
    // lane product, qubits 0..3 (qubit q -> lane bit 3-q)
    float lp = ((il & 8) ? sq[0] : cq[0]);
    lp      *= ((il & 4) ? sq[1] : cq[1]);
    lp      *= ((il & 2) ? sq[2] : cq[2]);
    lp      *= ((il & 1) ? sq[3] : cq[3]);
    // register tree, qubits 4..7 (reg bit3=q4, b2=q5, b1=q6, b0=q7)
    float t67[4] = {cq[6]*cq[7], cq[6]*sq[7], sq[6]*cq[7], sq[6]*sq[7]};
    float a5[2]  = {cq[5], sq[5]};
    float a4[2]  = {cq[4]*lp, sq[4]*lp};
    float ar[16], ai[16];
    #pragma unroll
    for (int r = 0; r < 16; ++r) {
        ar[r] = a4[(r >> 3) & 1] * a5[(r >> 2) & 1] * t67[r & 3];
        ai[r] = 0.f;
    }

    // ---- 4 layers of fused gates (CNOTs deferred) ----
    LAYER(0)
    LAYER(1)
    LAYER(2)
    LAYER(3)

    // ---- measurement ----
    float p[16];
    #pragma unroll
    for (int r = 0; r < 16; ++r) p[r] = ar[r]*ar[r] + ai[r]*ai[r];

    // register-level signed sums: A_k = sum_r (-1)^{bit k of r} p[r]
    float s0[8], d0[8];
    #pragma unroll
    for (int k = 0; k < 8; ++k) { s0[k] = p[2*k] + p[2*k+1]; d0[k] = p[2*k] - p[2*k+1]; }
    float A0 = ((d0[0]+d0[1]) + (d0[2]+d0[3])) + ((d0[4]+d0[5]) + (d0[6]+d0[7]));
    float s1[4], d1[4];
    #pragma unroll
    for (int k = 0; k < 4; ++k) { s1[k] = s0[2*k] + s0[2*k+1]; d1[k] = s0[2*k] - s0[2*k+1]; }
    float A1 = (d1[0]+d1[1]) + (d1[2]+d1[3]);
    float s2[2], d2[2];
    #pragma unroll
    for (int k = 0; k < 2; ++k) { s2[k] = s1[2*k] + s1[2*k+1]; d2[k] = s1[2*k] - s1[2*k+1]; }
    float A2 = d2[0] + d2[1];
    float A3 = s2[0] - s2[1];
    float P  = s2[0] + s2[1];

    // per-lane sign bitmasks for lane bits
    const unsigned sg1 = (unsigned)(il & 1) << 31;
    const unsigned sg2 = (unsigned)(il & 2) << 30;
    const unsigned sg4 = (unsigned)(il & 4) << 29;
    const unsigned sg8 = (unsigned)(il & 8) << 28;

    // 4-stage WHT of P over the 16-lane group: lane j holds sum_i (-1)^{i.j} P_i
    float wP = P;
    { float t = shx<1>(wP); wP = t + xsgn(wP, sg1); }
    { float t = shx<2>(wP); wP = t + xsgn(wP, sg2); }
    { float t = shx<4>(wP); wP = t + xsgn(wP, sg4); }
    { float t = shx<8>(wP); wP = t + xsgn(wP, sg8); }
    // v0 at il=8, v1 at il=4, v2 at il=2, v3 at il=1

    // signed lane sums for v4..v7 (sign = one lane bit), result in all lanes
    float a3 = xsgn(A3, sg8);
    a3 += shx<1>(a3); a3 += shx<2>(a3); a3 += shx<4>(a3); a3 += shx<8>(a3);
    float a2 = xsgn(A2, sg4);
    a2 += shx<1>(a2); a2 += shx<2>(a2); a2 += shx<4>(a2); a2 += shx<8>(a2);
    float a1 = xsgn(A1, sg2);
    a1 += shx<1>(a1); a1 += shx<2>(a1); a1 += shx<4>(a1); a1 += shx<8>(a1);
    float a0 = xsgn(A0, sg1);
    a0 += shx<1>(a0); a0 += shx<2>(a0); a0 += shx<4>(a0); a0 += shx<8>(a0);

    float* op = out + sample * 8;
    if (il == 8)      { op[0] = wP; op[4] = a3; }
    else if (il == 4) { op[1] = wP; op[5] = a2; }
    else if (il == 2) { op[2] = wP; op[6] = a1; }
    else if (il == 1) { op[3] = wP; op[7] = a0; }
}

extern "C" void kernel_launch(void* const* d_in, const int* in_sizes, int n_in,
                              void* d_out, int out_size, void* d_ws, size_t ws_size,
                              hipStream_t stream) {
    const float* x = (const float*)d_in[0];
    const float* w = (const float*)d_in[1];
    float* out = (float*)d_out;
    const int B = in_sizes[0] / 8;           // 16384 samples
    const int blocks = (B + 15) / 16;        // 16 samples per 256-thread block
    qsim<<<blocks, 256, 0, stream>>>(x, w, out, B);
}

// Round 2
// 78.549 us; speedup vs baseline: 1.1802x; 1.1802x over previous
//
#include <hip/hip_runtime.h>

// 8-qubit statevector sim. 4 samples per wave64: 16 lanes/sample, 16 amps/lane.
// Amp index i (8 bits): qubit q<=3 -> lane bit (3-q); qubit q>=4 -> reg bit (7-q).
// CNOT chains deferred into gate conjugation masks:
//   layer-l gate on qubit q pairs i with i^m, m = L^{-l} e_q  (components d, (l&d)==d)
//   row selector s = parity(i & row_q(L^l))                    (offsets d, selon(l,d))
// Fused U = RZ*RY*RX has u11 = conj(u00), u10 = -conj(u01)  =>  row selection is
// sign flips on Im(u00) and Re(u01) (xor 0x80000000), folded into coefficient pairs.
//
// R2 findings: full-DPP exchange regressed (48us, VALUBusy 74%) -> kernel is
// VALU-issue-bound, not DS-bound. R3 attacks VALU count directly:
//  * packed FP32: the complex gate update (nr,ni) is 4 VOP3P ops
//    (v_pk_mul_f32 + 3x v_pk_fma_f32 with op_sel/neg_lo) instead of 8 scalar,
//    with amps held as (re,im) VGPR pairs. Row-sign select = static choice of
//    coefficient pair (K0[v],K1[v]) -> the per-amp cndmasks disappear.
//  * exchange traffic split across pipes: single-DPP masks {1,2,3,7,8,15}
//    (11 of 16 cross-lane gates, bit-exact-validated in R1) on VALU DPP movs;
//    composite masks {4,5,6,10,12} (5 gates, 160 swz/wave) stay on ds_swizzle.

#define NGATES 32

typedef float v2f __attribute__((ext_vector_type(2)));

__device__ __forceinline__ v2f mk2(float a, float b) { v2f t; t.x = a; t.y = b; return t; }

constexpr bool selon(int l, int d) {
    return (l == 0) ? (d == 0) : (((d + l - 1) & (l - 1)) == (l - 1));
}
// pair mask, lane part (qubits 0..3 -> lane bit 3-q)
constexpr int lm_of(int l, int q) {
    int m = 0;
    for (int d = 0; q + d <= 7; ++d)
        if ((l & d) == d) { int qq = q + d; if (qq <= 3) m |= 1 << (3 - qq); }
    return m;
}
// pair mask, register part (qubits 4..7 -> reg bit 7-q)
constexpr int rm_of(int l, int q) {
    int m = 0;
    for (int d = 0; q + d <= 7; ++d)
        if ((l & d) == d) { int qq = q + d; if (qq >= 4) m |= 1 << (7 - qq); }
    return m;
}
// selector mask, lane part
constexpr int slm_of(int l, int q) {
    int m = 0;
    for (int d = 0; d <= q; ++d)
        if (selon(l, d)) { int k = q - d; if (k <= 3) m |= 1 << (3 - k); }
    return m;
}
// selector mask, register part
constexpr int srm_of(int l, int q) {
    int m = 0;
    for (int d = 0; d <= q; ++d)
        if (selon(l, d)) { int k = q - d; if (k >= 4) m |= 1 << (7 - k); }
    return m;
}

__device__ __forceinline__ float xsgn(float f, unsigned m) {
    return __int_as_float(__float_as_int(f) ^ (int)m);
}

// ---- cross-lane xor exchange: two implementations ----

// DPP: single mov for masks 1,2,3 (quad_perm), 7 (row_half_mirror),
// 8 (row_ror:8), 15 (row_mirror). Validated bit-exact in R1.
template<int C>
__device__ __forceinline__ int dppmov(int x) {
    return __builtin_amdgcn_update_dpp(x, x, C, 0xF, 0xF, false);
}
template<int M>
__device__ __forceinline__ float shx_dpp(float v) {
    int x = __float_as_int(v);
    if constexpr (M == 1)       { x = dppmov<0xB1>(x); }
    else if constexpr (M == 2)  { x = dppmov<0x4E>(x); }
    else if constexpr (M == 3)  { x = dppmov<0x1B>(x); }
    else if constexpr (M == 7)  { x = dppmov<0x141>(x); }
    else if constexpr (M == 8)  { x = dppmov<0x128>(x); }
    else                        { x = dppmov<0x140>(x); }  // 15
    return __int_as_float(x);
}
// DS pipe: immediate ds_swizzle, any mask 1..31 within 32-lane group
template<int M>
__device__ __forceinline__ float shx_ds(float v) {
    return __int_as_float(__builtin_amdgcn_ds_swizzle(__float_as_int(v), (M << 10) | 0x1F));
}
constexpr bool sgl(int M) {
    return M == 1 || M == 2 || M == 3 || M == 7 || M == 8 || M == 15;
}
template<int M>
__device__ __forceinline__ float shxm(float v) {
    if constexpr (sgl(M)) return shx_dpp<M>(v);
    else                  return shx_ds<M>(v);
}

// ---- packed complex gate update ----
// A=(ar,ai), B=(br,bi) partner, K0=(c0r, +/-c0i), K1=(+/-c1r, c1i).
// lo: c0r*ar - c0i*ai + c1r*br - c1i*bi
// hi: c0r*ai + c0i*ar + c1r*bi + c1i*br
// 4 VOP3P ops; op_sel swaps halves, neg_lo gives the conjugate minus signs.
__device__ __forceinline__ v2f cplx4(v2f K0, v2f K1, v2f A, v2f B) {
    v2f n;
    asm("v_pk_mul_f32 %0, %1, %2 op_sel:[0,0] op_sel_hi:[0,1]\n\t"
        "v_pk_fma_f32 %0, %1, %2, %0 op_sel:[1,1,0] op_sel_hi:[1,0,1] neg_lo:[1,0,0]\n\t"
        "v_pk_fma_f32 %0, %3, %4, %0 op_sel:[0,0,0] op_sel_hi:[0,1,1]\n\t"
        "v_pk_fma_f32 %0, %3, %4, %0 op_sel:[1,1,0] op_sel_hi:[1,0,1] neg_lo:[1,0,0]"
        : "=&v"(n)
        : "v"(K0), "v"(A), "v"(K1), "v"(B));
    return n;
}

template<int LM, int RM, int SLM, int SRM>
__device__ __forceinline__ void apply_gate(v2f A[16], int lane, const float4 g)
{
    unsigned sm = 0;
    if constexpr (SLM != 0)
        sm = (unsigned)((__builtin_popcount(lane & SLM) & 1) << 31);
    // coefficient pairs, row-variant v in {0,1}: K0[v]=(c0r, c0i_v), K1[v]=(c1r_v, c1i)
    v2f K0[2], K1[2];
    K0[0] = mk2(g.x, xsgn(g.y, sm));
    K0[1] = mk2(g.x, xsgn(g.y, sm ^ 0x80000000u));
    K1[0] = mk2(xsgn(g.z, sm), g.w);
    K1[1] = mk2(xsgn(g.z, sm ^ 0x80000000u), g.w);

    if constexpr (RM == 0) {
        // pure cross-lane: each r independent, partner = permuted self-register
        #pragma unroll
        for (int r = 0; r < 16; ++r) {
            const int v = __builtin_popcount(r & SRM) & 1;   // compile-time per r
            v2f B = mk2(shxm<LM>(A[r].x), shxm<LM>(A[r].y));
            A[r] = cplx4(K0[v], K1[v], A[r], B);
        }
    } else {
        // register pairs {r, r^RM}; fetch olds (permuted if LM!=0), update both
        #pragma unroll
        for (int r = 0; r < 16; ++r) {
            const int p = r ^ RM;
            if (p < r) continue;
            v2f Br, Bp;
            if constexpr (LM != 0) {
                Br = mk2(shxm<LM>(A[p].x), shxm<LM>(A[p].y));
                Bp = mk2(shxm<LM>(A[r].x), shxm<LM>(A[r].y));
            } else {
                Br = A[p];
                Bp = A[r];
            }
            const int vr = __builtin_popcount(r & SRM) & 1;
            const int vp = __builtin_popcount(p & SRM) & 1;
            v2f nr = cplx4(K0[vr], K1[vr], A[r], Br);
            v2f np = cplx4(K0[vp], K1[vp], A[p], Bp);
            A[r] = nr; A[p] = np;
        }
    }
}

#define GATE(L, Q) apply_gate<lm_of(L,Q), rm_of(L,Q), slm_of(L,Q), srm_of(L,Q)>( \
                       A, lane, gsh4[(L)*8+(Q)])
#define LAYER(L) GATE(L,0); GATE(L,1); GATE(L,2); GATE(L,3); \
                 GATE(L,4); GATE(L,5); GATE(L,6); GATE(L,7);

__global__ __launch_bounds__(256, 4) void qsim(const float* __restrict__ x,
                                               const float* __restrict__ w,
                                               float* __restrict__ out, int B)
{
    __shared__ float4 gsh4[NGATES];  // u00r,u00i,u01r,u01i (row1 = conj structure)

    const int tid = threadIdx.x;
    if (tid < NGATES) {
        float hx = 0.5f * w[tid*3+0];
        float hy = 0.5f * w[tid*3+1];
        float hz = 0.5f * w[tid*3+2];
        float cx = cosf(hx), sx = sinf(hx);
        float cy = cosf(hy), sy = sinf(hy);
        float cz = cosf(hz), sz = sinf(hz);
        // M = RY*RX ; U = RZ*M (row0 only; u11=conj(u00), u10=-conj(u01))
        float m00r = cy*cx,  m00i =  sy*sx;
        float m01r = -sy*cx, m01i = -cy*sx;
        gsh4[tid] = make_float4(cz*m00r + sz*m00i,
                                cz*m00i - sz*m00r,
                                cz*m01r + sz*m01i,
                                cz*m01i - sz*m01r);
    }
    __syncthreads();

    const int lane = tid & 63;
    const int il   = lane & 15;                 // in-sample lane index (amp bits 7:4)
    const int sample = blockIdx.x * 16 + (tid >> 4);
    if (sample >= B) return;

    // ---- encoding: product state ----
    const float4* xp = (const float4*)(x + sample * 8);
    float4 xa = xp[0], xb = xp[1];
    float xs[8] = {xa.x, xa.y, xa.z, xa.w, xb.x, xb.y, xb.z, xb.w};
    float cq[8], sq[8];
    #pragma unroll
    for (int q = 0; q < 8; ++q) {
        float h = 0.5f * xs[q];
        __sincosf(h, &sq[q], &cq[q]);
    }
    // lane product, qubits 0..3 (qubit q -> lane bit 3-q)
    float lp = ((il & 8) ? sq[0] : cq[0]);
    lp      *= ((il & 4) ? sq[1] : cq[1]);
    lp      *= ((il & 2) ? sq[2] : cq[2]);
    lp      *= ((il & 1) ? sq[3] : cq[3]);
    // register tree, qubits 4..7 (reg bit3=q4, b2=q5, b1=q6, b0=q7)
    float t67[4] = {cq[6]*cq[7], cq[6]*sq[7], sq[6]*cq[7], sq[6]*sq[7]};
    float a5[2]  = {cq[5], sq[5]};
    float a4[2]  = {cq[4]*lp, sq[4]*lp};
    v2f A[16];
    #pragma unroll
    for (int r = 0; r < 16; ++r)
        A[r] = mk2(a4[(r >> 3) & 1] * a5[(r >> 2) & 1] * t67[r & 3], 0.f);

    // ---- 4 layers of fused gates (CNOTs deferred) ----
    LAYER(0)
    LAYER(1)
    LAYER(2)
    LAYER(3)

    // ---- measurement ----
    float p[16];
    #pragma unroll
    for (int r = 0; r < 16; ++r) p[r] = A[r].x*A[r].x + A[r].y*A[r].y;

    // register-level signed sums: A_k = sum_r (-1)^{bit k of r} p[r]
    float s0[8], d0[8];
    #pragma unroll
    for (int k = 0; k < 8; ++k) { s0[k] = p[2*k] + p[2*k+1]; d0[k] = p[2*k] - p[2*k+1]; }
    float A0 = ((d0[0]+d0[1]) + (d0[2]+d0[3])) + ((d0[4]+d0[5]) + (d0[6]+d0[7]));
    float s1[4], d1[4];
    #pragma unroll
    for (int k = 0; k < 4; ++k) { s1[k] = s0[2*k] + s0[2*k+1]; d1[k] = s0[2*k] - s0[2*k+1]; }
    float A1 = (d1[0]+d1[1]) + (d1[2]+d1[3]);
    float s2[2], d2[2];
    #pragma unroll
    for (int k = 0; k < 2; ++k) { s2[k] = s1[2*k] + s1[2*k+1]; d2[k] = s1[2*k] - s1[2*k+1]; }
    float A2 = d2[0] + d2[1];
    float A3 = s2[0] - s2[1];
    float P  = s2[0] + s2[1];

    // per-lane sign bitmasks for lane bits
    const unsigned sg1 = (unsigned)(il & 1) << 31;
    const unsigned sg2 = (unsigned)(il & 2) << 30;
    const unsigned sg4 = (unsigned)(il & 4) << 29;
    const unsigned sg8 = (unsigned)(il & 8) << 28;

    // 4-stage WHT of P over the 16-lane group: lane j holds sum_i (-1)^{i.j} P_i
    float wP = P;
    { float t = shxm<1>(wP); wP = t + xsgn(wP, sg1); }
    { float t = shxm<2>(wP); wP = t + xsgn(wP, sg2); }
    { float t = shxm<4>(wP); wP = t + xsgn(wP, sg4); }
    { float t = shxm<8>(wP); wP = t + xsgn(wP, sg8); }
    // v0 at il=8, v1 at il=4, v2 at il=2, v3 at il=1

    // signed lane sums for v4..v7 (sign = one lane bit), result in all lanes
    float a3 = xsgn(A3, sg8);
    a3 += shxm<1>(a3); a3 += shxm<2>(a3); a3 += shxm<4>(a3); a3 += shxm<8>(a3);
    float a2 = xsgn(A2, sg4);
    a2 += shxm<1>(a2); a2 += shxm<2>(a2); a2 += shxm<4>(a2); a2 += shxm<8>(a2);
    float a1 = xsgn(A1, sg2);
    a1 += shxm<1>(a1); a1 += shxm<2>(a1); a1 += shxm<4>(a1); a1 += shxm<8>(a1);
    float a0 = xsgn(A0, sg1);
    a0 += shxm<1>(a0); a0 += shxm<2>(a0); a0 += shxm<4>(a0); a0 += shxm<8>(a0);

    float* op = out + sample * 8;
    if (il == 8)      { op[0] = wP; op[4] = a3; }
    else if (il == 4) { op[1] = wP; op[5] = a2; }
    else if (il == 2) { op[2] = wP; op[6] = a1; }
    else if (il == 1) { op[3] = wP; op[7] = a0; }
}

extern "C" void kernel_launch(void* const* d_in, const int* in_sizes, int n_in,
                              void* d_out, int out_size, void* d_ws, size_t ws_size,
                              hipStream_t stream) {
    const float* x = (const float*)d_in[0];
    const float* w = (const float*)d_in[1];
    float* out = (float*)d_out;
    const int B = in_sizes[0] / 8;           // 16384 samples
    const int blocks = (B + 15) / 16;        // 16 samples per 256-thread block
    qsim<<<blocks, 256, 0, stream>>>(x, w, out, B);
}